// Round 5
// baseline (4516.741 us; speedup 1.0000x reference)
//
#include <hip/hip_runtime.h>
#include <hip/hip_bf16.h>
#include <math.h>

#define L_SEQ 24
#define DT 1024
#define DM 256
#define NLAYER 12
#define NHEAD 4
#define HDIM 64
#define FFND 1024
#define NCLS 2
#define NBATCH 2048
#define NTOK (NBATCH*L_SEQ)   // 49152

typedef float f32x4 __attribute__((ext_vector_type(4)));
typedef __bf16 bf16x4 __attribute__((ext_vector_type(4)));
typedef __bf16 bf16x8 __attribute__((ext_vector_type(8)));

#define GLDS16(gp, lp) __builtin_amdgcn_global_load_lds((const __attribute__((address_space(1))) void*)(gp), (__attribute__((address_space(3))) void*)(lp), 16, 0, 0)

__device__ inline float wred_sum(float v){
#pragma unroll
  for (int o = 32; o > 0; o >>= 1) v += __shfl_xor(v, o);
  return v;
}
__device__ inline float wred_max(float v){
#pragma unroll
  for (int o = 32; o > 0; o >>= 1) v = fmaxf(v, __shfl_xor(v, o));
  return v;
}

// ---- [R][32]-bf16 LDS tiles, BK=32 ----
// Stage one 16-row x 32-col unit (1024B) via global_load_lds. LDS dest is
// linear from wave-uniform base (HW adds lane*16B): lane l -> row rowbase+l/4,
// phys 16B-slot l&3. Global source slot is XOR-swizzled: phys slot p of row r
// holds global slot p ^ ((r>>1)&3)  (rowbase must be a multiple of 16).
__device__ __forceinline__ void stage16x32(const __bf16* __restrict__ g, int ldk, int k0,
                                           __bf16* ldsbase, int lane, int rowbase){
  int r = rowbase + (lane >> 2);
  int cs = (lane & 3) ^ ((lane >> 3) & 3);
  GLDS16(g + (size_t)r*ldk + k0 + cs*8, ldsbase);
}
// Read one MFMA fragment (8 bf16 = global k-slot lane>>4) of row `row`.
__device__ __forceinline__ bf16x8 frag32(const __bf16* tile, int row, int lane){
  int p = (lane >> 4) ^ ((row >> 1) & 3);
  return *(const bf16x8*)(tile + (row << 5) + (p << 3));
}

// ---------------- weight fp32 -> bf16 convert ----------------
__global__ void cvt_bf16_kernel(const float* __restrict__ in, __bf16* __restrict__ out, int n4){
  int i = blockIdx.x * blockDim.x + threadIdx.x;
  int stride = gridDim.x * blockDim.x;
  for (; i < n4; i += stride){
    float4 v = ((const float4*)in)[i];
    bf16x4 o;
    o[0] = (__bf16)v.x; o[1] = (__bf16)v.y; o[2] = (__bf16)v.z; o[3] = (__bf16)v.w;
    ((bf16x4*)out)[i] = o;
  }
}

// ---------------- LN over 1024 (block per row) ----------------
__global__ __launch_bounds__(256) void ln1024_kernel(
    const float* __restrict__ in, const float* __restrict__ g, const float* __restrict__ bb,
    __bf16* __restrict__ out){
  int row = blockIdx.x;
  int tid = threadIdx.x, wid = tid >> 6, lane = tid & 63;
  float4 x = ((const float4*)(in + (size_t)row*DT))[tid];
  float s = x.x + x.y + x.z + x.w;
  float q = x.x*x.x + x.y*x.y + x.z*x.z + x.w*x.w;
  s = wred_sum(s); q = wred_sum(q);
  __shared__ float red[8];
  if (lane == 0){ red[wid] = s; red[4+wid] = q; }
  __syncthreads();
  s = red[0]+red[1]+red[2]+red[3];
  q = red[4]+red[5]+red[6]+red[7];
  float mean = s * (1.f/DT);
  float rstd = rsqrtf(q*(1.f/DT) - mean*mean + 1e-5f);
  float4 gv = ((const float4*)g)[tid], bv = ((const float4*)bb)[tid];
  bf16x4 o;
  o[0] = (__bf16)((x.x-mean)*rstd*gv.x + bv.x);
  o[1] = (__bf16)((x.y-mean)*rstd*gv.y + bv.y);
  o[2] = (__bf16)((x.z-mean)*rstd*gv.z + bv.z);
  o[3] = (__bf16)((x.w-mean)*rstd*gv.w + bv.w);
  ((bf16x4*)(out + (size_t)row*DT))[tid] = o;
}

// ---------------- RoPE + pre-LN + layer0 LN1, in place on z (wave per row) ----------------
__global__ __launch_bounds__(256) void rope_preln_kernel(
    float* __restrict__ z, const float* __restrict__ cosc, const float* __restrict__ sinc,
    const float* __restrict__ g, const float* __restrict__ bb,
    const float* __restrict__ g1, const float* __restrict__ b1, __bf16* __restrict__ xnb){
  int row = blockIdx.x*4 + (threadIdx.x >> 6);
  int lane = threadIdx.x & 63;
  int l = row % L_SEQ;
  float4 x = ((const float4*)(z + (size_t)row*DM))[lane];
  float4 p;
  p.x = __shfl_xor(x.x, 32); p.y = __shfl_xor(x.y, 32);
  p.z = __shfl_xor(x.z, 32); p.w = __shfl_xor(x.w, 32);
  float sgn = (lane < 32) ? -1.f : 1.f;
  float4 c = ((const float4*)(cosc + l*DM))[lane];
  float4 sn = ((const float4*)(sinc + l*DM))[lane];
  float4 xr;
  xr.x = x.x*c.x + sgn*p.x*sn.x;
  xr.y = x.y*c.y + sgn*p.y*sn.y;
  xr.z = x.z*c.z + sgn*p.z*sn.z;
  xr.w = x.w*c.w + sgn*p.w*sn.w;
  float s = wred_sum(xr.x + xr.y + xr.z + xr.w);
  float q = wred_sum(xr.x*xr.x + xr.y*xr.y + xr.z*xr.z + xr.w*xr.w);
  float mean = s * (1.f/DM);
  float rstd = rsqrtf(q*(1.f/DM) - mean*mean + 1e-5f);
  float4 gv = ((const float4*)g)[lane], bv = ((const float4*)bb)[lane];
  float4 y;
  y.x = (xr.x-mean)*rstd*gv.x + bv.x;
  y.y = (xr.y-mean)*rstd*gv.y + bv.y;
  y.z = (xr.z-mean)*rstd*gv.z + bv.z;
  y.w = (xr.w-mean)*rstd*gv.w + bv.w;
  ((float4*)(z + (size_t)row*DM))[lane] = y;
  float s2 = wred_sum(y.x + y.y + y.z + y.w);
  float q2 = wred_sum(y.x*y.x + y.y*y.y + y.z*y.z + y.w*y.w);
  float mean2 = s2 * (1.f/DM);
  float rstd2 = rsqrtf(q2*(1.f/DM) - mean2*mean2 + 1e-5f);
  float4 g1v = ((const float4*)g1)[lane], b1v = ((const float4*)b1)[lane];
  bf16x4 o;
  o[0] = (__bf16)((y.x-mean2)*rstd2*g1v.x + b1v.x);
  o[1] = (__bf16)((y.y-mean2)*rstd2*g1v.y + b1v.y);
  o[2] = (__bf16)((y.z-mean2)*rstd2*g1v.z + b1v.z);
  o[3] = (__bf16)((y.w-mean2)*rstd2*g1v.w + b1v.w);
  ((bf16x4*)(xnb + (size_t)row*DM))[lane] = o;
}

// ---------------- GEMM 128x128, 4 waves, BK=32 dbuf 2-phase ----------------
// C[M,N] = A[M,K] W[N,K]^T + bias.  mfma(W_frag, X_frag): n -> (lane>>4)*4+r,
// m -> lane&15 => vectorized epilogue.  MODE 0: store f32; MODE 1: bf16.
template<int MODE, int K>
__global__ __launch_bounds__(256) void gemm128_kernel(
    const __bf16* __restrict__ A, const __bf16* __restrict__ W,
    const float* __restrict__ bias,
    float* __restrict__ Cf, __bf16* __restrict__ Cb,
    int N, int nt){
  __shared__ __align__(16) __bf16 As[2][128*32];
  __shared__ __align__(16) __bf16 Bs[2][128*32];
  int bm = blockIdx.x / nt, bn = blockIdx.x % nt;
  int wid = threadIdx.x >> 6, lane = threadIdx.x & 63;
  int wr = wid >> 1, wc = wid & 1;
  int li = lane & 15, g4 = (lane >> 4) << 2;
  f32x4 acc[4][4] = {};
  const __bf16* ga = A + (size_t)bm*128*K;
  const __bf16* gb = W + (size_t)bn*128*K;
  const int NT = K/32;
  auto STAGE = [&](int b, int t){
    int k0 = t*32;
    stage16x32(ga, K, k0, &As[b][(wid*32)<<5],      lane, wid*32);
    stage16x32(ga, K, k0, &As[b][(wid*32+16)<<5],   lane, wid*32+16);
    stage16x32(gb, K, k0, &Bs[b][(wid*32)<<5],      lane, wid*32);
    stage16x32(gb, K, k0, &Bs[b][(wid*32+16)<<5],   lane, wid*32+16);
  };
  STAGE(0, 0);
  __syncthreads();
  int cur = 0;
  for (int t = 0; t < NT; t++){
    if (t + 1 < NT) STAGE(cur^1, t+1);
    bf16x8 xf[4], wf[4];
#pragma unroll
    for (int mi = 0; mi < 4; mi++) xf[mi] = frag32(As[cur], wr*64 + mi*16 + li, lane);
#pragma unroll
    for (int ni = 0; ni < 4; ni++) wf[ni] = frag32(Bs[cur], wc*64 + ni*16 + li, lane);
#pragma unroll
    for (int ni = 0; ni < 4; ni++)
#pragma unroll
      for (int mi = 0; mi < 4; mi++)
        acc[ni][mi] = __builtin_amdgcn_mfma_f32_16x16x32_bf16(wf[ni], xf[mi], acc[ni][mi], 0, 0, 0);
    __syncthreads();
    cur ^= 1;
  }
#pragma unroll
  for (int mi = 0; mi < 4; mi++){
    int m = bm*128 + wr*64 + mi*16 + li;
#pragma unroll
    for (int ni = 0; ni < 4; ni++){
      int n = bn*128 + wc*64 + ni*16 + g4;
      f32x4 bv = *(const f32x4*)(bias + n);
      f32x4 o = acc[ni][mi] + bv;
      if (MODE == 0){
        *(f32x4*)(Cf + (size_t)m*N + n) = o;
      } else {
        bf16x4 ob;
        ob[0] = (__bf16)o[0]; ob[1] = (__bf16)o[1]; ob[2] = (__bf16)o[2]; ob[3] = (__bf16)o[3];
        *(bf16x4*)(Cb + (size_t)m*N + n) = ob;
      }
    }
  }
}

// ---------------- fused w12 GEMM + SwiGLU, 128x128, BK=32 dbuf 2-phase ----------------
__global__ __launch_bounds__(256) void gemm_glu_kernel(
    const __bf16* __restrict__ A, const __bf16* __restrict__ W12,
    const float* __restrict__ bias, __bf16* __restrict__ H){
  __shared__ __align__(16) __bf16 As[2][128*32];
  __shared__ __align__(16) __bf16 B1s[2][128*32];
  __shared__ __align__(16) __bf16 B2s[2][128*32];
  const int K = 256;
  int bm = blockIdx.x >> 3, bn = blockIdx.x & 7;
  int wid = threadIdx.x >> 6, lane = threadIdx.x & 63;
  int wr = wid >> 1, wc = wid & 1;
  int li = lane & 15, g4 = (lane >> 4) << 2;
  f32x4 acc1[4][4] = {}, acc2[4][4] = {};
  const __bf16* ga  = A   + (size_t)bm*128*K;
  const __bf16* gb1 = W12 + (size_t)bn*128*K;
  const __bf16* gb2 = gb1 + (size_t)1024*K;
  auto STAGE = [&](int b, int t){
    int k0 = t*32;
    stage16x32(ga,  K, k0, &As[b][(wid*32)<<5],     lane, wid*32);
    stage16x32(ga,  K, k0, &As[b][(wid*32+16)<<5],  lane, wid*32+16);
    stage16x32(gb1, K, k0, &B1s[b][(wid*32)<<5],    lane, wid*32);
    stage16x32(gb1, K, k0, &B1s[b][(wid*32+16)<<5], lane, wid*32+16);
    stage16x32(gb2, K, k0, &B2s[b][(wid*32)<<5],    lane, wid*32);
    stage16x32(gb2, K, k0, &B2s[b][(wid*32+16)<<5], lane, wid*32+16);
  };
  STAGE(0, 0);
  __syncthreads();
  int cur = 0;
  for (int t = 0; t < 8; t++){
    if (t < 7) STAGE(cur^1, t+1);
    bf16x8 xf[4], w1f[4], w2f[4];
#pragma unroll
    for (int mi = 0; mi < 4; mi++) xf[mi] = frag32(As[cur], wr*64 + mi*16 + li, lane);
#pragma unroll
    for (int ni = 0; ni < 4; ni++){
      w1f[ni] = frag32(B1s[cur], wc*64 + ni*16 + li, lane);
      w2f[ni] = frag32(B2s[cur], wc*64 + ni*16 + li, lane);
    }
#pragma unroll
    for (int ni = 0; ni < 4; ni++)
#pragma unroll
      for (int mi = 0; mi < 4; mi++){
        acc1[ni][mi] = __builtin_amdgcn_mfma_f32_16x16x32_bf16(w1f[ni], xf[mi], acc1[ni][mi], 0, 0, 0);
        acc2[ni][mi] = __builtin_amdgcn_mfma_f32_16x16x32_bf16(w2f[ni], xf[mi], acc2[ni][mi], 0, 0, 0);
      }
    __syncthreads();
    cur ^= 1;
  }
#pragma unroll
  for (int mi = 0; mi < 4; mi++){
    int m = bm*128 + wr*64 + mi*16 + li;
#pragma unroll
    for (int ni = 0; ni < 4; ni++){
      int n = bn*128 + wc*64 + ni*16 + g4;
      f32x4 b1v = *(const f32x4*)(bias + n);
      f32x4 b2v = *(const f32x4*)(bias + 1024 + n);
      bf16x4 ob;
#pragma unroll
      for (int r = 0; r < 4; r++){
        float v1 = acc1[ni][mi][r] + b1v[r];
        float v2 = acc2[ni][mi][r] + b2v[r];
        float sig = 1.f/(1.f + __expf(-v1));
        ob[r] = (__bf16)(v1*sig*v2);
      }
      *(bf16x4*)(H + (size_t)m*FFND + n) = ob;
    }
  }
}

// ---------------- GEMM + residual + LayerNorm fused, BK=32 dbuf 2-phase ----------------
// BM=64, BN=256 (full row per block), 4 waves (wave w owns cols w*64..w*64+63).
// z[row] += A W^T + bias ; then LN(z row) -> outb (bf16) or outf (f32).
template<int K>
__global__ __launch_bounds__(256) void gemm_ln_kernel(
    const __bf16* __restrict__ A, const __bf16* __restrict__ W,
    const float* __restrict__ bias, float* __restrict__ z,
    const float* __restrict__ lng, const float* __restrict__ lnb,
    __bf16* __restrict__ outb, float* __restrict__ outf){
  __shared__ __align__(16) __bf16 As[2][64*32];
  __shared__ __align__(16) __bf16 Bs[2][256*32];
  __shared__ float redS[64][4], redQ[64][4];
  int bm = blockIdx.x;
  int wid = threadIdx.x >> 6, lane = threadIdx.x & 63;
  int li = lane & 15, g4 = (lane >> 4) << 2;
  f32x4 acc[4][4] = {};
  const __bf16* ga = A + (size_t)bm*64*K;
  const int NT = K/32;
  auto STAGE = [&](int b, int t){
    int k0 = t*32;
    stage16x32(ga, K, k0, &As[b][(wid*16)<<5], lane, wid*16);
#pragma unroll
    for (int j = 0; j < 4; j++)
      stage16x32(W, K, k0, &Bs[b][(wid*64 + j*16)<<5], lane, wid*64 + j*16);
  };
  STAGE(0, 0);
  __syncthreads();
  int cur = 0;
  for (int t = 0; t < NT; t++){
    if (t + 1 < NT) STAGE(cur^1, t+1);
    bf16x8 xf[4], wf[4];
#pragma unroll
    for (int mi = 0; mi < 4; mi++) xf[mi] = frag32(As[cur], mi*16 + li, lane);
#pragma unroll
    for (int ni = 0; ni < 4; ni++) wf[ni] = frag32(Bs[cur], wid*64 + ni*16 + li, lane);
#pragma unroll
    for (int ni = 0; ni < 4; ni++)
#pragma unroll
      for (int mi = 0; mi < 4; mi++)
        acc[ni][mi] = __builtin_amdgcn_mfma_f32_16x16x32_bf16(wf[ni], xf[mi], acc[ni][mi], 0, 0, 0);
    __syncthreads();
    cur ^= 1;
  }
  // residual add (vectorized) + row-stat accumulation
  float sA[4] = {}, qA[4] = {};
#pragma unroll
  for (int mi = 0; mi < 4; mi++){
    int m = bm*64 + mi*16 + li;
#pragma unroll
    for (int ni = 0; ni < 4; ni++){
      int n = wid*64 + ni*16 + g4;
      f32x4 zv = *(const f32x4*)(z + (size_t)m*DM + n);
      f32x4 bv = *(const f32x4*)(bias + n);
      f32x4 v = acc[ni][mi] + bv + zv;
      acc[ni][mi] = v;
      *(f32x4*)(z + (size_t)m*DM + n) = v;
#pragma unroll
      for (int r = 0; r < 4; r++){ sA[mi] += v[r]; qA[mi] += v[r]*v[r]; }
    }
  }
#pragma unroll
  for (int mi = 0; mi < 4; mi++){
    float s = sA[mi], q = qA[mi];
    s += __shfl_xor(s, 16); q += __shfl_xor(q, 16);
    s += __shfl_xor(s, 32); q += __shfl_xor(q, 32);
    if ((lane >> 4) == 0){ redS[mi*16 + li][wid] = s; redQ[mi*16 + li][wid] = q; }
  }
  __syncthreads();
#pragma unroll
  for (int mi = 0; mi < 4; mi++){
    int ml = mi*16 + li;
    float s = redS[ml][0] + redS[ml][1] + redS[ml][2] + redS[ml][3];
    float q = redQ[ml][0] + redQ[ml][1] + redQ[ml][2] + redQ[ml][3];
    float mean = s * (1.f/DM);
    float rstd = rsqrtf(q*(1.f/DM) - mean*mean + 1e-5f);
    int m = bm*64 + ml;
#pragma unroll
    for (int ni = 0; ni < 4; ni++){
      int n = wid*64 + ni*16 + g4;
      f32x4 gv = *(const f32x4*)(lng + n);
      f32x4 bv = *(const f32x4*)(lnb + n);
      if (outb){
        bf16x4 o;
#pragma unroll
        for (int r = 0; r < 4; r++) o[r] = (__bf16)((acc[ni][mi][r] - mean)*rstd*gv[r] + bv[r]);
        *(bf16x4*)(outb + (size_t)m*DM + n) = o;
      } else {
        f32x4 o;
#pragma unroll
        for (int r = 0; r < 4; r++) o[r] = (acc[ni][mi][r] - mean)*rstd*gv[r] + bv[r];
        *(f32x4*)(outf + (size_t)m*DM + n) = o;
      }
    }
  }
}

// ---------------- attention: block per sequence, wave per head ----------------
__global__ __launch_bounds__(256) void attn_kernel(const __bf16* __restrict__ qkv, __bf16* __restrict__ ob){
  int b = blockIdx.x;
  int h = threadIdx.x >> 6, lane = threadIdx.x & 63;
  __shared__ __align__(16) __bf16 Qs[NHEAD][L_SEQ][HDIM];
  __shared__ __align__(16) __bf16 Ks[NHEAD][L_SEQ][HDIM];
  __shared__ float Ps[NHEAD][L_SEQ][L_SEQ];
  const __bf16* base = qkv + (size_t)b*L_SEQ*768;
  float V[L_SEQ];
#pragma unroll
  for (int t = 0; t < L_SEQ; t++){
    int sw = lane ^ ((t & 7) << 3);
    Qs[h][t][sw] = base[t*768 + h*64 + lane];
    Ks[h][t][sw] = base[t*768 + 256 + h*64 + lane];
    V[t] = (float)base[t*768 + 512 + h*64 + lane];
  }
  __syncthreads();
  for (int p = lane; p < L_SEQ*L_SEQ; p += 64){
    int q = p / L_SEQ, k = p - q*L_SEQ;
    if (k <= q){
      int qx = (q & 7) << 3, kx = (k & 7) << 3;
      const __bf16* qr = Qs[h][q];
      const __bf16* kr = Ks[h][k];
      float s = 0.f;
#pragma unroll
      for (int d = 0; d < 64; d += 4){
        bf16x4 qa = *(const bf16x4*)(qr + (d ^ qx));
        bf16x4 ka = *(const bf16x4*)(kr + (d ^ kx));
        s += (float)qa[0]*(float)ka[0] + (float)qa[1]*(float)ka[1]
           + (float)qa[2]*(float)ka[2] + (float)qa[3]*(float)ka[3];
      }
      Ps[h][q][k] = s * 0.125f;
    }
  }
  __syncthreads();
  for (int q = 0; q < L_SEQ; q++){
    float v = (lane <= q) ? Ps[h][q][lane] : -1e30f;
    float mx = wred_max(v);
    float e = (lane <= q) ? __expf(v - mx) : 0.f;
    float sm = wred_sum(e);
    if (lane < L_SEQ) Ps[h][q][lane] = e / sm;
  }
  __syncthreads();
  for (int q = 0; q < L_SEQ; q++){
    float o = 0.f;
    for (int k = 0; k <= q; k++) o += Ps[h][q][k] * V[k];
    ob[((size_t)b*L_SEQ + q)*DM + h*64 + lane] = (__bf16)o;
  }
}

// ---------------- per-token heads ----------------
__global__ __launch_bounds__(256) void heads_kernel(
    const float* __restrict__ z,
    const float* __restrict__ cls_w, const float* __restrict__ cls_b,
    const float* __restrict__ eg_w1, const float* __restrict__ eg_b1,
    const float* __restrict__ eg_w2, const float* __restrict__ eg_b2,
    const float* __restrict__ halt_w, const float* __restrict__ halt_b,
    float* __restrict__ halt_out, float* __restrict__ cls_out){
  int m = blockIdx.x*4 + (threadIdx.x >> 6);
  int lane = threadIdx.x & 63;
  int l = m % L_SEQ;
  float4 zv = ((const float4*)(z + (size_t)m*DM))[lane];
  float4 w0 = ((const float4*)(cls_w + ((size_t)l*2 + 0)*DM))[lane];
  float4 w1 = ((const float4*)(cls_w + ((size_t)l*2 + 1)*DM))[lane];
  float c0 = wred_sum(zv.x*w0.x + zv.y*w0.y + zv.z*w0.z + zv.w*w0.w) + cls_b[l*2 + 0];
  float c1 = wred_sum(zv.x*w1.x + zv.y*w1.y + zv.z*w1.z + zv.w*w1.w) + cls_b[l*2 + 1];
  float mx = fmaxf(c0, c1);
  float e0 = __expf(c0 - mx), e1 = __expf(c1 - mx);
  float inv = 1.f/(e0 + e1);
  float p0 = fminf(fmaxf(e0*inv, 1e-10f), 1.f);
  float p1 = fminf(fmaxf(e1*inv, 1e-10f), 1.f);
  float ent = -(p0*__logf(p0) + p1*__logf(p1));
  float entn = fminf(fmaxf(ent * 1.44269504f, 0.f), 1.f);
  const float4* wg = (const float4*)(eg_w1 + ((size_t)l*DM + 4*lane)*8);
  float hacc[8] = {};
#pragma unroll
  for (int dd = 0; dd < 4; dd++){
    float zd = (dd==0) ? zv.x : (dd==1) ? zv.y : (dd==2) ? zv.z : zv.w;
    float4 a = wg[dd*2], b = wg[dd*2 + 1];
    hacc[0] += zd*a.x; hacc[1] += zd*a.y; hacc[2] += zd*a.z; hacc[3] += zd*a.w;
    hacc[4] += zd*b.x; hacc[5] += zd*b.y; hacc[6] += zd*b.z; hacc[7] += zd*b.w;
  }
  float gin = 0.f;
#pragma unroll
  for (int j = 0; j < 8; j++){
    float hj = wred_sum(hacc[j]);
    hj = tanhf(hj + eg_b1[l*8 + j]);
    gin += hj * eg_w2[l*8 + j];
  }
  gin += eg_b2[l];
  float gate = 1.f/(1.f + __expf(-gin));
  float gated = entn * gate;
  const float* hw = halt_w + (size_t)l*257;
  float hp = zv.x*hw[4*lane] + zv.y*hw[4*lane+1] + zv.z*hw[4*lane+2] + zv.w*hw[4*lane+3];
  float hl = wred_sum(hp) + gated*hw[256] + halt_b[l];
  if (lane == 0) halt_out[m] = hl;
  if (lane < 2) cls_out[(size_t)m*2 + lane] = lane ? c1 : c0;
}

extern "C" void kernel_launch(void* const* d_in, const int* in_sizes, int n_in,
                              void* d_out, int out_size, void* d_ws, size_t ws_size,
                              hipStream_t stream){
  const float* teacher = (const float*)d_in[0];
  const float* in_ln_g = (const float*)d_in[1];
  const float* in_ln_b = (const float*)d_in[2];
  const float* proj_w  = (const float*)d_in[3];
  const float* proj_b  = (const float*)d_in[4];
  const float* cosc    = (const float*)d_in[5];
  const float* sinc    = (const float*)d_in[6];
  const float* pre_g   = (const float*)d_in[7];
  const float* pre_b   = (const float*)d_in[8];
  const float* l_ln1_g = (const float*)d_in[9];
  const float* l_ln1_b = (const float*)d_in[10];
  const float* l_inw   = (const float*)d_in[11];
  const float* l_inb   = (const float*)d_in[12];
  const float* l_outw  = (const float*)d_in[13];
  const float* l_outb  = (const float*)d_in[14];
  const float* l_ln2_g = (const float*)d_in[15];
  const float* l_ln2_b = (const float*)d_in[16];
  const float* l_w12   = (const float*)d_in[17];
  const float* l_b12   = (const float*)d_in[18];
  const float* l_w3    = (const float*)d_in[19];
  const float* l_b3    = (const float*)d_in[20];
  const float* post_g  = (const float*)d_in[21];
  const float* post_b  = (const float*)d_in[22];
  const float* eg_w1   = (const float*)d_in[23];
  const float* eg_b1   = (const float*)d_in[24];
  const float* eg_w2   = (const float*)d_in[25];
  const float* eg_b2   = (const float*)d_in[26];
  const float* halt_w  = (const float*)d_in[27];
  const float* halt_b  = (const float*)d_in[28];
  const float* cls_w   = (const float*)d_in[29];
  const float* cls_b   = (const float*)d_in[30];

  float* out = (float*)d_out;
  float* halt_out = out;
  float* cls_out  = out + NTOK;
  float* z_out    = out + NTOK + (size_t)NTOK*NCLS;

  char* ws = (char*)d_ws;
  size_t off = 0;
  auto alloc = [&](size_t bytes){ void* p = ws + off; off += (bytes + 255) & ~(size_t)255; return p; };
  float*  zbuf = (float*) alloc((size_t)NTOK*DM*4);
  __bf16* xnb  = (__bf16*)alloc((size_t)NTOK*DM*2);
  __bf16* qkvb = (__bf16*)alloc((size_t)NTOK*768*2);
  __bf16* obuf = (__bf16*)alloc((size_t)NTOK*DM*2);
  __bf16* bigb = (__bf16*)alloc((size_t)NTOK*1024*2);
  __bf16* w_proj = (__bf16*)alloc((size_t)262144*2);
  __bf16* w_in   = (__bf16*)alloc((size_t)2359296*2);
  __bf16* w_out  = (__bf16*)alloc((size_t)786432*2);
  __bf16* w_12   = (__bf16*)alloc((size_t)6291456*2);
  __bf16* w_3    = (__bf16*)alloc((size_t)3145728*2);

  cvt_bf16_kernel<<<256, 256, 0, stream>>>(proj_w, w_proj, 262144/4);
  cvt_bf16_kernel<<<1024, 256, 0, stream>>>(l_inw, w_in, 2359296/4);
  cvt_bf16_kernel<<<512, 256, 0, stream>>>(l_outw, w_out, 786432/4);
  cvt_bf16_kernel<<<2048, 256, 0, stream>>>(l_w12, w_12, 6291456/4);
  cvt_bf16_kernel<<<1024, 256, 0, stream>>>(l_w3, w_3, 3145728/4);

  ln1024_kernel<<<NTOK, 256, 0, stream>>>(teacher, in_ln_g, in_ln_b, bigb);
  gemm128_kernel<0, 1024><<<384*2, 256, 0, stream>>>(bigb, w_proj, proj_b, zbuf, nullptr, 256, 2);
  rope_preln_kernel<<<NTOK/4, 256, 0, stream>>>(zbuf, cosc, sinc, pre_g, pre_b, l_ln1_g, l_ln1_b, xnb);

  for (int i = 0; i < NLAYER; i++){
    gemm128_kernel<1, 256><<<384*6, 256, 0, stream>>>(xnb, w_in + (size_t)i*768*256, l_inb + i*768, nullptr, qkvb, 768, 6);
    attn_kernel<<<NBATCH, 256, 0, stream>>>(qkvb, obuf);
    gemm_ln_kernel<256><<<NTOK/64, 256, 0, stream>>>(obuf, w_out + (size_t)i*256*256, l_outb + i*256,
                                                     zbuf, l_ln2_g + i*256, l_ln2_b + i*256, xnb, nullptr);
    gemm_glu_kernel<<<384*8, 256, 0, stream>>>(xnb, w_12 + (size_t)i*2048*256, l_b12 + i*2048, bigb);
    bool last = (i == NLAYER-1);
    gemm_ln_kernel<1024><<<NTOK/64, 256, 0, stream>>>(bigb, w_3 + (size_t)i*256*1024, l_b3 + i*256,
                                                      zbuf,
                                                      last ? post_g : l_ln1_g + (i+1)*256,
                                                      last ? post_b : l_ln1_b + (i+1)*256,
                                                      last ? nullptr : xnb,
                                                      last ? z_out : nullptr);
  }

  heads_kernel<<<NTOK/4, 256, 0, stream>>>(z_out, cls_w, cls_b, eg_w1, eg_b1, eg_w2, eg_b2,
                                           halt_w, halt_b, halt_out, cls_out);
}

// Round 6
// 4092.500 us; speedup vs baseline: 1.1037x; 1.1037x over previous
//
#include <hip/hip_runtime.h>
#include <hip/hip_bf16.h>
#include <math.h>

#define L_SEQ 24
#define DT 1024
#define DM 256
#define NLAYER 12
#define NHEAD 4
#define HDIM 64
#define FFND 1024
#define NCLS 2
#define NBATCH 2048
#define NTOK (NBATCH*L_SEQ)   // 49152

typedef float f32x4 __attribute__((ext_vector_type(4)));
typedef __bf16 bf16x4 __attribute__((ext_vector_type(4)));
typedef __bf16 bf16x8 __attribute__((ext_vector_type(8)));

#define GLDS16(gp, lp) __builtin_amdgcn_global_load_lds((const __attribute__((address_space(1))) void*)(gp), (__attribute__((address_space(3))) void*)(lp), 16, 0, 0)
// Counted waits (T4): never drain vmcnt to 0 in the main loop.
#define VMWAIT(N) asm volatile("s_waitcnt vmcnt(" #N ")" ::: "memory")
#define LGKM0()   asm volatile("s_waitcnt lgkmcnt(0)" ::: "memory")

__device__ inline float wred_sum(float v){
#pragma unroll
  for (int o = 32; o > 0; o >>= 1) v += __shfl_xor(v, o);
  return v;
}
__device__ inline float wred_max(float v){
#pragma unroll
  for (int o = 32; o > 0; o >>= 1) v = fmaxf(v, __shfl_xor(v, o));
  return v;
}

// ---- [R][32]-bf16 LDS tiles, BK=32 ----
// Stage one 16-row x 32-col unit (1024B) via global_load_lds. LDS dest is
// linear from wave-uniform base (HW adds lane*16B): lane l -> row rowbase+l/4,
// phys 16B-slot l&3. Global source slot is XOR-swizzled: phys slot p of row r
// holds global slot p ^ ((r>>1)&3)  (rowbase must be a multiple of 16).
__device__ __forceinline__ void stage16x32(const __bf16* __restrict__ g, int ldk, int k0,
                                           __bf16* ldsbase, int lane, int rowbase){
  int r = rowbase + (lane >> 2);
  int cs = (lane & 3) ^ ((lane >> 3) & 3);
  GLDS16(g + (size_t)r*ldk + k0 + cs*8, ldsbase);
}
// Read one MFMA fragment (8 bf16 = global k-slot lane>>4) of row `row`.
__device__ __forceinline__ bf16x8 frag32(const __bf16* tile, int row, int lane){
  int p = (lane >> 4) ^ ((row >> 1) & 3);
  return *(const bf16x8*)(tile + (row << 5) + (p << 3));
}

// XCD-aware swizzle (T1): consecutive WORK ids land on the same XCD's L2.
// Requires gridDim.x % 8 == 0 (all call sites satisfy this).
__device__ __forceinline__ int xcd_work(){
  int nwg = gridDim.x, bid = blockIdx.x;
  return (bid & 7) * (nwg >> 3) + (bid >> 3);
}

// ---------------- weight fp32 -> bf16 convert ----------------
__global__ void cvt_bf16_kernel(const float* __restrict__ in, __bf16* __restrict__ out, int n4){
  int i = blockIdx.x * blockDim.x + threadIdx.x;
  int stride = gridDim.x * blockDim.x;
  for (; i < n4; i += stride){
    float4 v = ((const float4*)in)[i];
    bf16x4 o;
    o[0] = (__bf16)v.x; o[1] = (__bf16)v.y; o[2] = (__bf16)v.z; o[3] = (__bf16)v.w;
    ((bf16x4*)out)[i] = o;
  }
}

// ---------------- LN over 1024 (block per row) ----------------
__global__ __launch_bounds__(256) void ln1024_kernel(
    const float* __restrict__ in, const float* __restrict__ g, const float* __restrict__ bb,
    __bf16* __restrict__ out){
  int row = blockIdx.x;
  int tid = threadIdx.x, wid = tid >> 6, lane = tid & 63;
  float4 x = ((const float4*)(in + (size_t)row*DT))[tid];
  float s = x.x + x.y + x.z + x.w;
  float q = x.x*x.x + x.y*x.y + x.z*x.z + x.w*x.w;
  s = wred_sum(s); q = wred_sum(q);
  __shared__ float red[8];
  if (lane == 0){ red[wid] = s; red[4+wid] = q; }
  __syncthreads();
  s = red[0]+red[1]+red[2]+red[3];
  q = red[4]+red[5]+red[6]+red[7];
  float mean = s * (1.f/DT);
  float rstd = rsqrtf(q*(1.f/DT) - mean*mean + 1e-5f);
  float4 gv = ((const float4*)g)[tid], bv = ((const float4*)bb)[tid];
  bf16x4 o;
  o[0] = (__bf16)((x.x-mean)*rstd*gv.x + bv.x);
  o[1] = (__bf16)((x.y-mean)*rstd*gv.y + bv.y);
  o[2] = (__bf16)((x.z-mean)*rstd*gv.z + bv.z);
  o[3] = (__bf16)((x.w-mean)*rstd*gv.w + bv.w);
  ((bf16x4*)(out + (size_t)row*DT))[tid] = o;
}

// ---------------- RoPE + pre-LN + layer0 LN1, in place on z (wave per row) ----------------
__global__ __launch_bounds__(256) void rope_preln_kernel(
    float* __restrict__ z, const float* __restrict__ cosc, const float* __restrict__ sinc,
    const float* __restrict__ g, const float* __restrict__ bb,
    const float* __restrict__ g1, const float* __restrict__ b1, __bf16* __restrict__ xnb){
  int row = blockIdx.x*4 + (threadIdx.x >> 6);
  int lane = threadIdx.x & 63;
  int l = row % L_SEQ;
  float4 x = ((const float4*)(z + (size_t)row*DM))[lane];
  float4 p;
  p.x = __shfl_xor(x.x, 32); p.y = __shfl_xor(x.y, 32);
  p.z = __shfl_xor(x.z, 32); p.w = __shfl_xor(x.w, 32);
  float sgn = (lane < 32) ? -1.f : 1.f;
  float4 c = ((const float4*)(cosc + l*DM))[lane];
  float4 sn = ((const float4*)(sinc + l*DM))[lane];
  float4 xr;
  xr.x = x.x*c.x + sgn*p.x*sn.x;
  xr.y = x.y*c.y + sgn*p.y*sn.y;
  xr.z = x.z*c.z + sgn*p.z*sn.z;
  xr.w = x.w*c.w + sgn*p.w*sn.w;
  float s = wred_sum(xr.x + xr.y + xr.z + xr.w);
  float q = wred_sum(xr.x*xr.x + xr.y*xr.y + xr.z*xr.z + xr.w*xr.w);
  float mean = s * (1.f/DM);
  float rstd = rsqrtf(q*(1.f/DM) - mean*mean + 1e-5f);
  float4 gv = ((const float4*)g)[lane], bv = ((const float4*)bb)[lane];
  float4 y;
  y.x = (xr.x-mean)*rstd*gv.x + bv.x;
  y.y = (xr.y-mean)*rstd*gv.y + bv.y;
  y.z = (xr.z-mean)*rstd*gv.z + bv.z;
  y.w = (xr.w-mean)*rstd*gv.w + bv.w;
  ((float4*)(z + (size_t)row*DM))[lane] = y;
  float s2 = wred_sum(y.x + y.y + y.z + y.w);
  float q2 = wred_sum(y.x*y.x + y.y*y.y + y.z*y.z + y.w*y.w);
  float mean2 = s2 * (1.f/DM);
  float rstd2 = rsqrtf(q2*(1.f/DM) - mean2*mean2 + 1e-5f);
  float4 g1v = ((const float4*)g1)[lane], b1v = ((const float4*)b1)[lane];
  bf16x4 o;
  o[0] = (__bf16)((y.x-mean2)*rstd2*g1v.x + b1v.x);
  o[1] = (__bf16)((y.y-mean2)*rstd2*g1v.y + b1v.y);
  o[2] = (__bf16)((y.z-mean2)*rstd2*g1v.z + b1v.z);
  o[3] = (__bf16)((y.w-mean2)*rstd2*g1v.w + b1v.w);
  ((bf16x4*)(xnb + (size_t)row*DM))[lane] = o;
}

// ---------------- GEMM 128x128, 4 waves, BK=32, counted-vmcnt pipeline ----------------
// C[M,N] = A[M,K] W[N,K]^T + bias.  mfma(W_frag, X_frag): n -> (lane>>4)*4+r,
// m -> lane&15 => vectorized epilogue.  MODE 0: store f32; MODE 1: bf16.
// Pipeline: chunks t,t+1 in flight; vmcnt(4) counted; raw barriers (no drain).
template<int MODE, int K>
__global__ __launch_bounds__(256) void gemm128_kernel(
    const __bf16* __restrict__ A, const __bf16* __restrict__ W,
    const float* __restrict__ bias,
    float* __restrict__ Cf, __bf16* __restrict__ Cb,
    int N, int nt){
  __shared__ __align__(16) __bf16 As[2][128*32];
  __shared__ __align__(16) __bf16 Bs[2][128*32];
  int work = xcd_work();
  int bm = work / nt, bn = work % nt;
  int wid = threadIdx.x >> 6, lane = threadIdx.x & 63;
  int wr = wid >> 1, wc = wid & 1;
  int li = lane & 15, g4 = (lane >> 4) << 2;
  f32x4 acc[4][4] = {};
  const __bf16* ga = A + (size_t)bm*128*K;
  const __bf16* gb = W + (size_t)bn*128*K;
  const int NT = K/32;
  auto STAGE = [&](int b, int t){   // 4 GLDS16 per lane
    int k0 = t*32;
    stage16x32(ga, K, k0, &As[b][(wid*32)<<5],      lane, wid*32);
    stage16x32(ga, K, k0, &As[b][(wid*32+16)<<5],   lane, wid*32+16);
    stage16x32(gb, K, k0, &Bs[b][(wid*32)<<5],      lane, wid*32);
    stage16x32(gb, K, k0, &Bs[b][(wid*32+16)<<5],   lane, wid*32+16);
  };
  STAGE(0, 0);
  STAGE(1, 1);
  int cur = 0;
  for (int t = 0; t < NT; t++){
    if (t + 1 < NT) { VMWAIT(4); } else { VMWAIT(0); }   // own chunk-t loads landed
    __builtin_amdgcn_s_barrier();                        // everyone's chunk-t landed
    bf16x8 xf[4], wf[4];
#pragma unroll
    for (int mi = 0; mi < 4; mi++) xf[mi] = frag32(As[cur], wr*64 + mi*16 + li, lane);
#pragma unroll
    for (int ni = 0; ni < 4; ni++) wf[ni] = frag32(Bs[cur], wc*64 + ni*16 + li, lane);
    LGKM0();
    __builtin_amdgcn_sched_barrier(0);
    __builtin_amdgcn_s_barrier();                        // all waves done reading buf[cur]
    if (t + 2 < NT) STAGE(cur, t+2);                     // overwrite freed buffer
    __builtin_amdgcn_s_setprio(1);
#pragma unroll
    for (int ni = 0; ni < 4; ni++)
#pragma unroll
      for (int mi = 0; mi < 4; mi++)
        acc[ni][mi] = __builtin_amdgcn_mfma_f32_16x16x32_bf16(wf[ni], xf[mi], acc[ni][mi], 0, 0, 0);
    __builtin_amdgcn_s_setprio(0);
    cur ^= 1;
  }
#pragma unroll
  for (int mi = 0; mi < 4; mi++){
    int m = bm*128 + wr*64 + mi*16 + li;
#pragma unroll
    for (int ni = 0; ni < 4; ni++){
      int n = bn*128 + wc*64 + ni*16 + g4;
      f32x4 bv = *(const f32x4*)(bias + n);
      f32x4 o = acc[ni][mi] + bv;
      if (MODE == 0){
        *(f32x4*)(Cf + (size_t)m*N + n) = o;
      } else {
        bf16x4 ob;
        ob[0] = (__bf16)o[0]; ob[1] = (__bf16)o[1]; ob[2] = (__bf16)o[2]; ob[3] = (__bf16)o[3];
        *(bf16x4*)(Cb + (size_t)m*N + n) = ob;
      }
    }
  }
}

// ---------------- fused w12 GEMM + SwiGLU, 128x128, counted-vmcnt pipeline ----------------
__global__ __launch_bounds__(256) void gemm_glu_kernel(
    const __bf16* __restrict__ A, const __bf16* __restrict__ W12,
    const float* __restrict__ bias, __bf16* __restrict__ H){
  __shared__ __align__(16) __bf16 As[2][128*32];
  __shared__ __align__(16) __bf16 B1s[2][128*32];
  __shared__ __align__(16) __bf16 B2s[2][128*32];
  const int K = 256;
  int work = xcd_work();
  int bm = work >> 3, bn = work & 7;
  int wid = threadIdx.x >> 6, lane = threadIdx.x & 63;
  int wr = wid >> 1, wc = wid & 1;
  int li = lane & 15, g4 = (lane >> 4) << 2;
  f32x4 acc1[4][4] = {}, acc2[4][4] = {};
  const __bf16* ga  = A   + (size_t)bm*128*K;
  const __bf16* gb1 = W12 + (size_t)bn*128*K;
  const __bf16* gb2 = gb1 + (size_t)1024*K;
  auto STAGE = [&](int b, int t){   // 6 GLDS16 per lane
    int k0 = t*32;
    stage16x32(ga,  K, k0, &As[b][(wid*32)<<5],     lane, wid*32);
    stage16x32(ga,  K, k0, &As[b][(wid*32+16)<<5],  lane, wid*32+16);
    stage16x32(gb1, K, k0, &B1s[b][(wid*32)<<5],    lane, wid*32);
    stage16x32(gb1, K, k0, &B1s[b][(wid*32+16)<<5], lane, wid*32+16);
    stage16x32(gb2, K, k0, &B2s[b][(wid*32)<<5],    lane, wid*32);
    stage16x32(gb2, K, k0, &B2s[b][(wid*32+16)<<5], lane, wid*32+16);
  };
  STAGE(0, 0);
  STAGE(1, 1);
  int cur = 0;
  for (int t = 0; t < 8; t++){
    if (t + 1 < 8) { VMWAIT(6); } else { VMWAIT(0); }
    __builtin_amdgcn_s_barrier();
    bf16x8 xf[4], w1f[4], w2f[4];
#pragma unroll
    for (int mi = 0; mi < 4; mi++) xf[mi] = frag32(As[cur], wr*64 + mi*16 + li, lane);
#pragma unroll
    for (int ni = 0; ni < 4; ni++){
      w1f[ni] = frag32(B1s[cur], wc*64 + ni*16 + li, lane);
      w2f[ni] = frag32(B2s[cur], wc*64 + ni*16 + li, lane);
    }
    LGKM0();
    __builtin_amdgcn_sched_barrier(0);
    __builtin_amdgcn_s_barrier();
    if (t + 2 < 8) STAGE(cur, t+2);
    __builtin_amdgcn_s_setprio(1);
#pragma unroll
    for (int ni = 0; ni < 4; ni++)
#pragma unroll
      for (int mi = 0; mi < 4; mi++){
        acc1[ni][mi] = __builtin_amdgcn_mfma_f32_16x16x32_bf16(w1f[ni], xf[mi], acc1[ni][mi], 0, 0, 0);
        acc2[ni][mi] = __builtin_amdgcn_mfma_f32_16x16x32_bf16(w2f[ni], xf[mi], acc2[ni][mi], 0, 0, 0);
      }
    __builtin_amdgcn_s_setprio(0);
    cur ^= 1;
  }
#pragma unroll
  for (int mi = 0; mi < 4; mi++){
    int m = bm*128 + wr*64 + mi*16 + li;
#pragma unroll
    for (int ni = 0; ni < 4; ni++){
      int n = bn*128 + wc*64 + ni*16 + g4;
      f32x4 b1v = *(const f32x4*)(bias + n);
      f32x4 b2v = *(const f32x4*)(bias + 1024 + n);
      bf16x4 ob;
#pragma unroll
      for (int r = 0; r < 4; r++){
        float v1 = acc1[ni][mi][r] + b1v[r];
        float v2 = acc2[ni][mi][r] + b2v[r];
        float sig = 1.f/(1.f + __expf(-v1));
        ob[r] = (__bf16)(v1*sig*v2);
      }
      *(bf16x4*)(H + (size_t)m*FFND + n) = ob;
    }
  }
}

// ---------------- GEMM + residual + LayerNorm fused, counted-vmcnt pipeline ----------------
// BM=64, BN=256 (full row per block), 4 waves (wave w owns cols w*64..w*64+63).
// z[row] += A W^T + bias ; then LN(z row) -> outb (bf16) or outf (f32).
template<int K>
__global__ __launch_bounds__(256) void gemm_ln_kernel(
    const __bf16* __restrict__ A, const __bf16* __restrict__ W,
    const float* __restrict__ bias, float* __restrict__ z,
    const float* __restrict__ lng, const float* __restrict__ lnb,
    __bf16* __restrict__ outb, float* __restrict__ outf){
  __shared__ __align__(16) __bf16 As[2][64*32];
  __shared__ __align__(16) __bf16 Bs[2][256*32];
  __shared__ float redS[64][4], redQ[64][4];
  int bm = blockIdx.x;
  int wid = threadIdx.x >> 6, lane = threadIdx.x & 63;
  int li = lane & 15, g4 = (lane >> 4) << 2;
  f32x4 acc[4][4] = {};
  const __bf16* ga = A + (size_t)bm*64*K;
  const int NT = K/32;
  auto STAGE = [&](int b, int t){   // 5 GLDS16 per lane
    int k0 = t*32;
    stage16x32(ga, K, k0, &As[b][(wid*16)<<5], lane, wid*16);
#pragma unroll
    for (int j = 0; j < 4; j++)
      stage16x32(W, K, k0, &Bs[b][(wid*64 + j*16)<<5], lane, wid*64 + j*16);
  };
  STAGE(0, 0);
  STAGE(1, 1);
  int cur = 0;
  for (int t = 0; t < NT; t++){
    if (t + 1 < NT) { VMWAIT(5); } else { VMWAIT(0); }
    __builtin_amdgcn_s_barrier();
    bf16x8 xf[4], wf[4];
#pragma unroll
    for (int mi = 0; mi < 4; mi++) xf[mi] = frag32(As[cur], mi*16 + li, lane);
#pragma unroll
    for (int ni = 0; ni < 4; ni++) wf[ni] = frag32(Bs[cur], wid*64 + ni*16 + li, lane);
    LGKM0();
    __builtin_amdgcn_sched_barrier(0);
    __builtin_amdgcn_s_barrier();
    if (t + 2 < NT) STAGE(cur, t+2);
    __builtin_amdgcn_s_setprio(1);
#pragma unroll
    for (int ni = 0; ni < 4; ni++)
#pragma unroll
      for (int mi = 0; mi < 4; mi++)
        acc[ni][mi] = __builtin_amdgcn_mfma_f32_16x16x32_bf16(wf[ni], xf[mi], acc[ni][mi], 0, 0, 0);
    __builtin_amdgcn_s_setprio(0);
    cur ^= 1;
  }
  // residual add (vectorized) + row-stat accumulation
  float sA[4] = {}, qA[4] = {};
#pragma unroll
  for (int mi = 0; mi < 4; mi++){
    int m = bm*64 + mi*16 + li;
#pragma unroll
    for (int ni = 0; ni < 4; ni++){
      int n = wid*64 + ni*16 + g4;
      f32x4 zv = *(const f32x4*)(z + (size_t)m*DM + n);
      f32x4 bv = *(const f32x4*)(bias + n);
      f32x4 v = acc[ni][mi] + bv + zv;
      acc[ni][mi] = v;
      *(f32x4*)(z + (size_t)m*DM + n) = v;
#pragma unroll
      for (int r = 0; r < 4; r++){ sA[mi] += v[r]; qA[mi] += v[r]*v[r]; }
    }
  }
  __syncthreads();   // re-sync before LDS reduction reuse
#pragma unroll
  for (int mi = 0; mi < 4; mi++){
    float s = sA[mi], q = qA[mi];
    s += __shfl_xor(s, 16); q += __shfl_xor(q, 16);
    s += __shfl_xor(s, 32); q += __shfl_xor(q, 32);
    if ((lane >> 4) == 0){ redS[mi*16 + li][wid] = s; redQ[mi*16 + li][wid] = q; }
  }
  __syncthreads();
#pragma unroll
  for (int mi = 0; mi < 4; mi++){
    int ml = mi*16 + li;
    float s = redS[ml][0] + redS[ml][1] + redS[ml][2] + redS[ml][3];
    float q = redQ[ml][0] + redQ[ml][1] + redQ[ml][2] + redQ[ml][3];
    float mean = s * (1.f/DM);
    float rstd = rsqrtf(q*(1.f/DM) - mean*mean + 1e-5f);
    int m = bm*64 + ml;
#pragma unroll
    for (int ni = 0; ni < 4; ni++){
      int n = wid*64 + ni*16 + g4;
      f32x4 gv = *(const f32x4*)(lng + n);
      f32x4 bv = *(const f32x4*)(lnb + n);
      if (outb){
        bf16x4 o;
#pragma unroll
        for (int r = 0; r < 4; r++) o[r] = (__bf16)((acc[ni][mi][r] - mean)*rstd*gv[r] + bv[r]);
        *(bf16x4*)(outb + (size_t)m*DM + n) = o;
      } else {
        f32x4 o;
#pragma unroll
        for (int r = 0; r < 4; r++) o[r] = (acc[ni][mi][r] - mean)*rstd*gv[r] + bv[r];
        *(f32x4*)(outf + (size_t)m*DM + n) = o;
      }
    }
  }
}

// ---------------- attention: block per sequence, wave per head ----------------
__global__ __launch_bounds__(256) void attn_kernel(const __bf16* __restrict__ qkv, __bf16* __restrict__ ob){
  int b = blockIdx.x;
  int h = threadIdx.x >> 6, lane = threadIdx.x & 63;
  __shared__ __align__(16) __bf16 Qs[NHEAD][L_SEQ][HDIM];
  __shared__ __align__(16) __bf16 Ks[NHEAD][L_SEQ][HDIM];
  __shared__ float Ps[NHEAD][L_SEQ][L_SEQ];
  const __bf16* base = qkv + (size_t)b*L_SEQ*768;
  float V[L_SEQ];
#pragma unroll
  for (int t = 0; t < L_SEQ; t++){
    int sw = lane ^ ((t & 7) << 3);
    Qs[h][t][sw] = base[t*768 + h*64 + lane];
    Ks[h][t][sw] = base[t*768 + 256 + h*64 + lane];
    V[t] = (float)base[t*768 + 512 + h*64 + lane];
  }
  __syncthreads();
  for (int p = lane; p < L_SEQ*L_SEQ; p += 64){
    int q = p / L_SEQ, k = p - q*L_SEQ;
    if (k <= q){
      int qx = (q & 7) << 3, kx = (k & 7) << 3;
      const __bf16* qr = Qs[h][q];
      const __bf16* kr = Ks[h][k];
      float s = 0.f;
#pragma unroll
      for (int d = 0; d < 64; d += 4){
        bf16x4 qa = *(const bf16x4*)(qr + (d ^ qx));
        bf16x4 ka = *(const bf16x4*)(kr + (d ^ kx));
        s += (float)qa[0]*(float)ka[0] + (float)qa[1]*(float)ka[1]
           + (float)qa[2]*(float)ka[2] + (float)qa[3]*(float)ka[3];
      }
      Ps[h][q][k] = s * 0.125f;
    }
  }
  __syncthreads();
  for (int q = 0; q < L_SEQ; q++){
    float v = (lane <= q) ? Ps[h][q][lane] : -1e30f;
    float mx = wred_max(v);
    float e = (lane <= q) ? __expf(v - mx) : 0.f;
    float sm = wred_sum(e);
    if (lane < L_SEQ) Ps[h][q][lane] = e / sm;
  }
  __syncthreads();
  for (int q = 0; q < L_SEQ; q++){
    float o = 0.f;
    for (int k = 0; k <= q; k++) o += Ps[h][q][k] * V[k];
    ob[((size_t)b*L_SEQ + q)*DM + h*64 + lane] = (__bf16)o;
  }
}

// ---------------- per-token heads ----------------
__global__ __launch_bounds__(256) void heads_kernel(
    const float* __restrict__ z,
    const float* __restrict__ cls_w, const float* __restrict__ cls_b,
    const float* __restrict__ eg_w1, const float* __restrict__ eg_b1,
    const float* __restrict__ eg_w2, const float* __restrict__ eg_b2,
    const float* __restrict__ halt_w, const float* __restrict__ halt_b,
    float* __restrict__ halt_out, float* __restrict__ cls_out){
  int m = blockIdx.x*4 + (threadIdx.x >> 6);
  int lane = threadIdx.x & 63;
  int l = m % L_SEQ;
  float4 zv = ((const float4*)(z + (size_t)m*DM))[lane];
  float4 w0 = ((const float4*)(cls_w + ((size_t)l*2 + 0)*DM))[lane];
  float4 w1 = ((const float4*)(cls_w + ((size_t)l*2 + 1)*DM))[lane];
  float c0 = wred_sum(zv.x*w0.x + zv.y*w0.y + zv.z*w0.z + zv.w*w0.w) + cls_b[l*2 + 0];
  float c1 = wred_sum(zv.x*w1.x + zv.y*w1.y + zv.z*w1.z + zv.w*w1.w) + cls_b[l*2 + 1];
  float mx = fmaxf(c0, c1);
  float e0 = __expf(c0 - mx), e1 = __expf(c1 - mx);
  float inv = 1.f/(e0 + e1);
  float p0 = fminf(fmaxf(e0*inv, 1e-10f), 1.f);
  float p1 = fminf(fmaxf(e1*inv, 1e-10f), 1.f);
  float ent = -(p0*__logf(p0) + p1*__logf(p1));
  float entn = fminf(fmaxf(ent * 1.44269504f, 0.f), 1.f);
  const float4* wg = (const float4*)(eg_w1 + ((size_t)l*DM + 4*lane)*8);
  float hacc[8] = {};
#pragma unroll
  for (int dd = 0; dd < 4; dd++){
    float zd = (dd==0) ? zv.x : (dd==1) ? zv.y : (dd==2) ? zv.z : zv.w;
    float4 a = wg[dd*2], b = wg[dd*2 + 1];
    hacc[0] += zd*a.x; hacc[1] += zd*a.y; hacc[2] += zd*a.z; hacc[3] += zd*a.w;
    hacc[4] += zd*b.x; hacc[5] += zd*b.y; hacc[6] += zd*b.z; hacc[7] += zd*b.w;
  }
  float gin = 0.f;
#pragma unroll
  for (int j = 0; j < 8; j++){
    float hj = wred_sum(hacc[j]);
    hj = tanhf(hj + eg_b1[l*8 + j]);
    gin += hj * eg_w2[l*8 + j];
  }
  gin += eg_b2[l];
  float gate = 1.f/(1.f + __expf(-gin));
  float gated = entn * gate;
  const float* hw = halt_w + (size_t)l*257;
  float hp = zv.x*hw[4*lane] + zv.y*hw[4*lane+1] + zv.z*hw[4*lane+2] + zv.w*hw[4*lane+3];
  float hl = wred_sum(hp) + gated*hw[256] + halt_b[l];
  if (lane == 0) halt_out[m] = hl;
  if (lane < 2) cls_out[(size_t)m*2 + lane] = lane ? c1 : c0;
}

extern "C" void kernel_launch(void* const* d_in, const int* in_sizes, int n_in,
                              void* d_out, int out_size, void* d_ws, size_t ws_size,
                              hipStream_t stream){
  const float* teacher = (const float*)d_in[0];
  const float* in_ln_g = (const float*)d_in[1];
  const float* in_ln_b = (const float*)d_in[2];
  const float* proj_w  = (const float*)d_in[3];
  const float* proj_b  = (const float*)d_in[4];
  const float* cosc    = (const float*)d_in[5];
  const float* sinc    = (const float*)d_in[6];
  const float* pre_g   = (const float*)d_in[7];
  const float* pre_b   = (const float*)d_in[8];
  const float* l_ln1_g = (const float*)d_in[9];
  const float* l_ln1_b = (const float*)d_in[10];
  const float* l_inw   = (const float*)d_in[11];
  const float* l_inb   = (const float*)d_in[12];
  const float* l_outw  = (const float*)d_in[13];
  const float* l_outb  = (const float*)d_in[14];
  const float* l_ln2_g = (const float*)d_in[15];
  const float* l_ln2_b = (const float*)d_in[16];
  const float* l_w12   = (const float*)d_in[17];
  const float* l_b12   = (const float*)d_in[18];
  const float* l_w3    = (const float*)d_in[19];
  const float* l_b3    = (const float*)d_in[20];
  const float* post_g  = (const float*)d_in[21];
  const float* post_b  = (const float*)d_in[22];
  const float* eg_w1   = (const float*)d_in[23];
  const float* eg_b1   = (const float*)d_in[24];
  const float* eg_w2   = (const float*)d_in[25];
  const float* eg_b2   = (const float*)d_in[26];
  const float* halt_w  = (const float*)d_in[27];
  const float* halt_b  = (const float*)d_in[28];
  const float* cls_w   = (const float*)d_in[29];
  const float* cls_b   = (const float*)d_in[30];

  float* out = (float*)d_out;
  float* halt_out = out;
  float* cls_out  = out + NTOK;
  float* z_out    = out + NTOK + (size_t)NTOK*NCLS;

  char* ws = (char*)d_ws;
  size_t off = 0;
  auto alloc = [&](size_t bytes){ void* p = ws + off; off += (bytes + 255) & ~(size_t)255; return p; };
  float*  zbuf = (float*) alloc((size_t)NTOK*DM*4);
  __bf16* xnb  = (__bf16*)alloc((size_t)NTOK*DM*2);
  __bf16* qkvb = (__bf16*)alloc((size_t)NTOK*768*2);
  __bf16* obuf = (__bf16*)alloc((size_t)NTOK*DM*2);
  __bf16* bigb = (__bf16*)alloc((size_t)NTOK*1024*2);
  __bf16* w_proj = (__bf16*)alloc((size_t)262144*2);
  __bf16* w_in   = (__bf16*)alloc((size_t)2359296*2);
  __bf16* w_out  = (__bf16*)alloc((size_t)786432*2);
  __bf16* w_12   = (__bf16*)alloc((size_t)6291456*2);
  __bf16* w_3    = (__bf16*)alloc((size_t)3145728*2);

  cvt_bf16_kernel<<<256, 256, 0, stream>>>(proj_w, w_proj, 262144/4);
  cvt_bf16_kernel<<<1024, 256, 0, stream>>>(l_inw, w_in, 2359296/4);
  cvt_bf16_kernel<<<512, 256, 0, stream>>>(l_outw, w_out, 786432/4);
  cvt_bf16_kernel<<<2048, 256, 0, stream>>>(l_w12, w_12, 6291456/4);
  cvt_bf16_kernel<<<1024, 256, 0, stream>>>(l_w3, w_3, 3145728/4);

  ln1024_kernel<<<NTOK, 256, 0, stream>>>(teacher, in_ln_g, in_ln_b, bigb);
  gemm128_kernel<0, 1024><<<384*2, 256, 0, stream>>>(bigb, w_proj, proj_b, zbuf, nullptr, 256, 2);
  rope_preln_kernel<<<NTOK/4, 256, 0, stream>>>(zbuf, cosc, sinc, pre_g, pre_b, l_ln1_g, l_ln1_b, xnb);

  for (int i = 0; i < NLAYER; i++){
    gemm128_kernel<1, 256><<<384*6, 256, 0, stream>>>(xnb, w_in + (size_t)i*768*256, l_inb + i*768, nullptr, qkvb, 768, 6);
    attn_kernel<<<NBATCH, 256, 0, stream>>>(qkvb, obuf);
    gemm_ln_kernel<256><<<NTOK/64, 256, 0, stream>>>(obuf, w_out + (size_t)i*256*256, l_outb + i*256,
                                                     zbuf, l_ln2_g + i*256, l_ln2_b + i*256, xnb, nullptr);
    gemm_glu_kernel<<<384*8, 256, 0, stream>>>(xnb, w_12 + (size_t)i*2048*256, l_b12 + i*2048, bigb);
    bool last = (i == NLAYER-1);
    gemm_ln_kernel<1024><<<NTOK/64, 256, 0, stream>>>(bigb, w_3 + (size_t)i*256*1024, l_b3 + i*256,
                                                      zbuf,
                                                      last ? post_g : l_ln1_g + (i+1)*256,
                                                      last ? post_b : l_ln1_b + (i+1)*256,
                                                      last ? nullptr : xnb,
                                                      last ? z_out : nullptr);
  }

  heads_kernel<<<NTOK/4, 256, 0, stream>>>(z_out, cls_w, cls_b, eg_w1, eg_b1, eg_w2, eg_b2,
                                           halt_w, halt_b, halt_out, cls_out);
}

// Round 7
// 3941.504 us; speedup vs baseline: 1.1459x; 1.0383x over previous
//
#include <hip/hip_runtime.h>
#include <hip/hip_bf16.h>
#include <math.h>

#define L_SEQ 24
#define DT 1024
#define DM 256
#define NLAYER 12
#define NHEAD 4
#define HDIM 64
#define FFND 1024
#define NCLS 2
#define NBATCH 2048
#define NTOK (NBATCH*L_SEQ)   // 49152

typedef float f32x4 __attribute__((ext_vector_type(4)));
typedef __bf16 bf16x4 __attribute__((ext_vector_type(4)));
typedef __bf16 bf16x8 __attribute__((ext_vector_type(8)));

#define GLDS16(gp, lp) __builtin_amdgcn_global_load_lds((const __attribute__((address_space(1))) void*)(gp), (__attribute__((address_space(3))) void*)(lp), 16, 0, 0)
// Counted waits (T4): never drain vmcnt to 0 in the main loop.
#define VMWAIT(N) asm volatile("s_waitcnt vmcnt(" #N ")" ::: "memory")
#define LGKM0()   asm volatile("s_waitcnt lgkmcnt(0)" ::: "memory")

__device__ inline float wred_sum(float v){
#pragma unroll
  for (int o = 32; o > 0; o >>= 1) v += __shfl_xor(v, o);
  return v;
}
__device__ inline float wred_max(float v){
#pragma unroll
  for (int o = 32; o > 0; o >>= 1) v = fmaxf(v, __shfl_xor(v, o));
  return v;
}

// ---- [R][32]-bf16 LDS tiles, BK=32 ----
// Stage one 16-row x 32-col unit (1024B) via global_load_lds; LDS dest linear
// (HW adds lane*16B), global source slot XOR-swizzled (both-sides rule #21).
__device__ __forceinline__ void stage16x32(const __bf16* __restrict__ g, int ldk, int k0,
                                           __bf16* ldsbase, int lane, int rowbase){
  int r = rowbase + (lane >> 2);
  int cs = (lane & 3) ^ ((lane >> 3) & 3);
  GLDS16(g + (size_t)r*ldk + k0 + cs*8, ldsbase);
}
// Read one MFMA fragment (8 bf16 = global k-slot lane>>4) of row `row`.
__device__ __forceinline__ bf16x8 frag32(const __bf16* tile, int row, int lane){
  int p = (lane >> 4) ^ ((row >> 1) & 3);
  return *(const bf16x8*)(tile + (row << 5) + (p << 3));
}

// XCD-aware swizzle (T1). Requires gridDim.x % 8 == 0 (all call sites comply).
__device__ __forceinline__ int xcd_work(){
  int nwg = gridDim.x, bid = blockIdx.x;
  return (bid & 7) * (nwg >> 3) + (bid >> 3);
}

// ---------------- weight fp32 -> bf16 convert ----------------
__global__ void cvt_bf16_kernel(const float* __restrict__ in, __bf16* __restrict__ out, int n4){
  int i = blockIdx.x * blockDim.x + threadIdx.x;
  int stride = gridDim.x * blockDim.x;
  for (; i < n4; i += stride){
    float4 v = ((const float4*)in)[i];
    bf16x4 o;
    o[0] = (__bf16)v.x; o[1] = (__bf16)v.y; o[2] = (__bf16)v.z; o[3] = (__bf16)v.w;
    ((bf16x4*)out)[i] = o;
  }
}

// ---------------- LN over 1024 (block per row) ----------------
__global__ __launch_bounds__(256) void ln1024_kernel(
    const float* __restrict__ in, const float* __restrict__ g, const float* __restrict__ bb,
    __bf16* __restrict__ out){
  int row = blockIdx.x;
  int tid = threadIdx.x, wid = tid >> 6, lane = tid & 63;
  float4 x = ((const float4*)(in + (size_t)row*DT))[tid];
  float s = x.x + x.y + x.z + x.w;
  float q = x.x*x.x + x.y*x.y + x.z*x.z + x.w*x.w;
  s = wred_sum(s); q = wred_sum(q);
  __shared__ float red[8];
  if (lane == 0){ red[wid] = s; red[4+wid] = q; }
  __syncthreads();
  s = red[0]+red[1]+red[2]+red[3];
  q = red[4]+red[5]+red[6]+red[7];
  float mean = s * (1.f/DT);
  float rstd = rsqrtf(q*(1.f/DT) - mean*mean + 1e-5f);
  float4 gv = ((const float4*)g)[tid], bv = ((const float4*)bb)[tid];
  bf16x4 o;
  o[0] = (__bf16)((x.x-mean)*rstd*gv.x + bv.x);
  o[1] = (__bf16)((x.y-mean)*rstd*gv.y + bv.y);
  o[2] = (__bf16)((x.z-mean)*rstd*gv.z + bv.z);
  o[3] = (__bf16)((x.w-mean)*rstd*gv.w + bv.w);
  ((bf16x4*)(out + (size_t)row*DT))[tid] = o;
}

// ---------------- RoPE + pre-LN + layer0 LN1, in place on z (wave per row) ----------------
__global__ __launch_bounds__(256) void rope_preln_kernel(
    float* __restrict__ z, const float* __restrict__ cosc, const float* __restrict__ sinc,
    const float* __restrict__ g, const float* __restrict__ bb,
    const float* __restrict__ g1, const float* __restrict__ b1, __bf16* __restrict__ xnb){
  int row = blockIdx.x*4 + (threadIdx.x >> 6);
  int lane = threadIdx.x & 63;
  int l = row % L_SEQ;
  float4 x = ((const float4*)(z + (size_t)row*DM))[lane];
  float4 p;
  p.x = __shfl_xor(x.x, 32); p.y = __shfl_xor(x.y, 32);
  p.z = __shfl_xor(x.z, 32); p.w = __shfl_xor(x.w, 32);
  float sgn = (lane < 32) ? -1.f : 1.f;
  float4 c = ((const float4*)(cosc + l*DM))[lane];
  float4 sn = ((const float4*)(sinc + l*DM))[lane];
  float4 xr;
  xr.x = x.x*c.x + sgn*p.x*sn.x;
  xr.y = x.y*c.y + sgn*p.y*sn.y;
  xr.z = x.z*c.z + sgn*p.z*sn.z;
  xr.w = x.w*c.w + sgn*p.w*sn.w;
  float s = wred_sum(xr.x + xr.y + xr.z + xr.w);
  float q = wred_sum(xr.x*xr.x + xr.y*xr.y + xr.z*xr.z + xr.w*xr.w);
  float mean = s * (1.f/DM);
  float rstd = rsqrtf(q*(1.f/DM) - mean*mean + 1e-5f);
  float4 gv = ((const float4*)g)[lane], bv = ((const float4*)bb)[lane];
  float4 y;
  y.x = (xr.x-mean)*rstd*gv.x + bv.x;
  y.y = (xr.y-mean)*rstd*gv.y + bv.y;
  y.z = (xr.z-mean)*rstd*gv.z + bv.z;
  y.w = (xr.w-mean)*rstd*gv.w + bv.w;
  ((float4*)(z + (size_t)row*DM))[lane] = y;
  float s2 = wred_sum(y.x + y.y + y.z + y.w);
  float q2 = wred_sum(y.x*y.x + y.y*y.y + y.z*y.z + y.w*y.w);
  float mean2 = s2 * (1.f/DM);
  float rstd2 = rsqrtf(q2*(1.f/DM) - mean2*mean2 + 1e-5f);
  float4 g1v = ((const float4*)g1)[lane], b1v = ((const float4*)b1)[lane];
  bf16x4 o;
  o[0] = (__bf16)((y.x-mean2)*rstd2*g1v.x + b1v.x);
  o[1] = (__bf16)((y.y-mean2)*rstd2*g1v.y + b1v.y);
  o[2] = (__bf16)((y.z-mean2)*rstd2*g1v.z + b1v.z);
  o[3] = (__bf16)((y.w-mean2)*rstd2*g1v.w + b1v.w);
  ((bf16x4*)(xnb + (size_t)row*DM))[lane] = o;
}

// ---------------- GEMM 256x256, 8 waves, BK=32, counted-vmcnt pipeline ----------------
// C[M,N] = A[M,K] W[N,K]^T + bias.  Wave grid 4Mx2N, wave tile 64x128.
// mfma(W_frag, X_frag): n -> (lane>>4)*4+r (consecutive), m -> lane&15.
// MODE 0: store f32; MODE 1: store bf16.
template<int MODE, int K>
__global__ __launch_bounds__(512) void gemm512_kernel(
    const __bf16* __restrict__ A, const __bf16* __restrict__ W,
    const float* __restrict__ bias,
    float* __restrict__ Cf, __bf16* __restrict__ Cb,
    int N, int nt){
  __shared__ __align__(16) __bf16 As[2][256*32];
  __shared__ __align__(16) __bf16 Bs[2][256*32];
  int work = xcd_work();
  int bm = work / nt, bn = work % nt;
  int wid = threadIdx.x >> 6, lane = threadIdx.x & 63;
  int wr = wid >> 1, wc = wid & 1;           // 4 M-groups x 2 N-groups
  int li = lane & 15, g4 = (lane >> 4) << 2;
  f32x4 acc[8][4] = {};
  const __bf16* ga = A + (size_t)bm*256*K;
  const __bf16* gb = W + (size_t)bn*256*K;
  const int NT = K/32;
  auto STAGE = [&](int b, int t){   // 4 GLDS16 per lane (A: waves 0-3, B: waves 4-7)
    int k0 = t*32;
    if (wid < 4){
#pragma unroll
      for (int j = 0; j < 4; j++){ int r = (wid*4 + j)*16; stage16x32(ga, K, k0, &As[b][r<<5], lane, r); }
    } else {
#pragma unroll
      for (int j = 0; j < 4; j++){ int r = ((wid-4)*4 + j)*16; stage16x32(gb, K, k0, &Bs[b][r<<5], lane, r); }
    }
  };
  STAGE(0, 0);
  STAGE(1, 1);
  int cur = 0;
  for (int t = 0; t < NT; t++){
    if (t + 1 < NT) { VMWAIT(4); } else { VMWAIT(0); }
    __builtin_amdgcn_s_barrier();
    bf16x8 xf[4], wf[8];
#pragma unroll
    for (int mi = 0; mi < 4; mi++) xf[mi] = frag32(As[cur], wr*64 + mi*16 + li, lane);
#pragma unroll
    for (int ni = 0; ni < 8; ni++) wf[ni] = frag32(Bs[cur], wc*128 + ni*16 + li, lane);
    LGKM0();
    __builtin_amdgcn_sched_barrier(0);
    __builtin_amdgcn_s_barrier();
    if (t + 2 < NT) STAGE(cur, t+2);
    __builtin_amdgcn_s_setprio(1);
#pragma unroll
    for (int ni = 0; ni < 8; ni++)
#pragma unroll
      for (int mi = 0; mi < 4; mi++)
        acc[ni][mi] = __builtin_amdgcn_mfma_f32_16x16x32_bf16(wf[ni], xf[mi], acc[ni][mi], 0, 0, 0);
    __builtin_amdgcn_s_setprio(0);
    cur ^= 1;
  }
#pragma unroll
  for (int mi = 0; mi < 4; mi++){
    int m = bm*256 + wr*64 + mi*16 + li;
#pragma unroll
    for (int ni = 0; ni < 8; ni++){
      int n = bn*256 + wc*128 + ni*16 + g4;
      f32x4 bv = *(const f32x4*)(bias + n);
      f32x4 o = acc[ni][mi] + bv;
      if (MODE == 0){
        *(f32x4*)(Cf + (size_t)m*N + n) = o;
      } else {
        bf16x4 ob;
        ob[0] = (__bf16)o[0]; ob[1] = (__bf16)o[1]; ob[2] = (__bf16)o[2]; ob[3] = (__bf16)o[3];
        *(bf16x4*)(Cb + (size_t)m*N + n) = ob;
      }
    }
  }
}

// ---------------- fused w12 GEMM + SwiGLU, 256x128, 8 waves, counted-vmcnt ----------------
// Wave grid 4Mx2N, wave tile 64x64 per gemm (two gemms share A-frags).
__global__ __launch_bounds__(512) void gemm_glu_kernel(
    const __bf16* __restrict__ A, const __bf16* __restrict__ W12,
    const float* __restrict__ bias, __bf16* __restrict__ H){
  __shared__ __align__(16) __bf16 As[2][256*32];
  __shared__ __align__(16) __bf16 B1s[2][128*32];
  __shared__ __align__(16) __bf16 B2s[2][128*32];
  const int K = 256;
  int work = xcd_work();
  int bm = work >> 3, bn = work & 7;
  int wid = threadIdx.x >> 6, lane = threadIdx.x & 63;
  int wr = wid >> 1, wc = wid & 1;
  int li = lane & 15, g4 = (lane >> 4) << 2;
  f32x4 acc1[4][4] = {}, acc2[4][4] = {};
  const __bf16* ga  = A   + (size_t)bm*256*K;
  const __bf16* gb1 = W12 + (size_t)bn*128*K;
  const __bf16* gb2 = gb1 + (size_t)1024*K;
  auto STAGE = [&](int b, int t){   // 4 GLDS16 per lane
    int k0 = t*32;
    if (wid < 4){
#pragma unroll
      for (int j = 0; j < 4; j++){ int r = (wid*4 + j)*16; stage16x32(ga, K, k0, &As[b][r<<5], lane, r); }
    } else if (wid < 6){
#pragma unroll
      for (int j = 0; j < 4; j++){ int r = ((wid-4)*4 + j)*16; stage16x32(gb1, K, k0, &B1s[b][r<<5], lane, r); }
    } else {
#pragma unroll
      for (int j = 0; j < 4; j++){ int r = ((wid-6)*4 + j)*16; stage16x32(gb2, K, k0, &B2s[b][r<<5], lane, r); }
    }
  };
  STAGE(0, 0);
  STAGE(1, 1);
  int cur = 0;
  for (int t = 0; t < 8; t++){
    if (t + 1 < 8) { VMWAIT(4); } else { VMWAIT(0); }
    __builtin_amdgcn_s_barrier();
    bf16x8 xf[4], w1f[4], w2f[4];
#pragma unroll
    for (int mi = 0; mi < 4; mi++) xf[mi] = frag32(As[cur], wr*64 + mi*16 + li, lane);
#pragma unroll
    for (int ni = 0; ni < 4; ni++){
      w1f[ni] = frag32(B1s[cur], wc*64 + ni*16 + li, lane);
      w2f[ni] = frag32(B2s[cur], wc*64 + ni*16 + li, lane);
    }
    LGKM0();
    __builtin_amdgcn_sched_barrier(0);
    __builtin_amdgcn_s_barrier();
    if (t + 2 < 8) STAGE(cur, t+2);
    __builtin_amdgcn_s_setprio(1);
#pragma unroll
    for (int ni = 0; ni < 4; ni++)
#pragma unroll
      for (int mi = 0; mi < 4; mi++){
        acc1[ni][mi] = __builtin_amdgcn_mfma_f32_16x16x32_bf16(w1f[ni], xf[mi], acc1[ni][mi], 0, 0, 0);
        acc2[ni][mi] = __builtin_amdgcn_mfma_f32_16x16x32_bf16(w2f[ni], xf[mi], acc2[ni][mi], 0, 0, 0);
      }
    __builtin_amdgcn_s_setprio(0);
    cur ^= 1;
  }
#pragma unroll
  for (int mi = 0; mi < 4; mi++){
    int m = bm*256 + wr*64 + mi*16 + li;
#pragma unroll
    for (int ni = 0; ni < 4; ni++){
      int n = bn*128 + wc*64 + ni*16 + g4;
      f32x4 b1v = *(const f32x4*)(bias + n);
      f32x4 b2v = *(const f32x4*)(bias + 1024 + n);
      bf16x4 ob;
#pragma unroll
      for (int r = 0; r < 4; r++){
        float v1 = acc1[ni][mi][r] + b1v[r];
        float v2 = acc2[ni][mi][r] + b2v[r];
        float sig = 1.f/(1.f + __expf(-v1));
        ob[r] = (__bf16)(v1*sig*v2);
      }
      *(bf16x4*)(H + (size_t)m*FFND + n) = ob;
    }
  }
}

// ---------------- GEMM 256x256 + residual + LayerNorm, 8 waves, counted-vmcnt -----------
// BN=256 = full row per block.  z[row] += A W^T + bias; LN -> outb (bf16) or outf (f32).
template<int K>
__global__ __launch_bounds__(512) void gemm_ln_kernel(
    const __bf16* __restrict__ A, const __bf16* __restrict__ W,
    const float* __restrict__ bias, float* __restrict__ z,
    const float* __restrict__ lng, const float* __restrict__ lnb,
    __bf16* __restrict__ outb, float* __restrict__ outf){
  __shared__ __align__(16) __bf16 As[2][256*32];
  __shared__ __align__(16) __bf16 Bs[2][256*32];
  __shared__ float redS[256][2], redQ[256][2];
  int bm = xcd_work();
  int wid = threadIdx.x >> 6, lane = threadIdx.x & 63;
  int wr = wid >> 1, wc = wid & 1;
  int li = lane & 15, g4 = (lane >> 4) << 2;
  f32x4 acc[8][4] = {};
  const __bf16* ga = A + (size_t)bm*256*K;
  const int NT = K/32;
  auto STAGE = [&](int b, int t){   // 4 GLDS16 per lane
    int k0 = t*32;
    if (wid < 4){
#pragma unroll
      for (int j = 0; j < 4; j++){ int r = (wid*4 + j)*16; stage16x32(ga, K, k0, &As[b][r<<5], lane, r); }
    } else {
#pragma unroll
      for (int j = 0; j < 4; j++){ int r = ((wid-4)*4 + j)*16; stage16x32(W, K, k0, &Bs[b][r<<5], lane, r); }
    }
  };
  STAGE(0, 0);
  STAGE(1, 1);
  int cur = 0;
  for (int t = 0; t < NT; t++){
    if (t + 1 < NT) { VMWAIT(4); } else { VMWAIT(0); }
    __builtin_amdgcn_s_barrier();
    bf16x8 xf[4], wf[8];
#pragma unroll
    for (int mi = 0; mi < 4; mi++) xf[mi] = frag32(As[cur], wr*64 + mi*16 + li, lane);
#pragma unroll
    for (int ni = 0; ni < 8; ni++) wf[ni] = frag32(Bs[cur], wc*128 + ni*16 + li, lane);
    LGKM0();
    __builtin_amdgcn_sched_barrier(0);
    __builtin_amdgcn_s_barrier();
    if (t + 2 < NT) STAGE(cur, t+2);
    __builtin_amdgcn_s_setprio(1);
#pragma unroll
    for (int ni = 0; ni < 8; ni++)
#pragma unroll
      for (int mi = 0; mi < 4; mi++)
        acc[ni][mi] = __builtin_amdgcn_mfma_f32_16x16x32_bf16(wf[ni], xf[mi], acc[ni][mi], 0, 0, 0);
    __builtin_amdgcn_s_setprio(0);
    cur ^= 1;
  }
  // residual add (vectorized) + row-stat accumulation
  float sA[4] = {}, qA[4] = {};
#pragma unroll
  for (int mi = 0; mi < 4; mi++){
    int m = bm*256 + wr*64 + mi*16 + li;
#pragma unroll
    for (int ni = 0; ni < 8; ni++){
      int n = wc*128 + ni*16 + g4;
      f32x4 zv = *(const f32x4*)(z + (size_t)m*DM + n);
      f32x4 bv = *(const f32x4*)(bias + n);
      f32x4 v = acc[ni][mi] + bv + zv;
      acc[ni][mi] = v;
      *(f32x4*)(z + (size_t)m*DM + n) = v;
#pragma unroll
      for (int r = 0; r < 4; r++){ sA[mi] += v[r]; qA[mi] += v[r]*v[r]; }
    }
  }
  __syncthreads();   // drain pipeline before reusing LDS banks for reduction
#pragma unroll
  for (int mi = 0; mi < 4; mi++){
    float s = sA[mi], q = qA[mi];
    s += __shfl_xor(s, 16); q += __shfl_xor(q, 16);
    s += __shfl_xor(s, 32); q += __shfl_xor(q, 32);
    if (lane < 16){ redS[wr*64 + mi*16 + li][wc] = s; redQ[wr*64 + mi*16 + li][wc] = q; }
  }
  __syncthreads();
#pragma unroll
  for (int mi = 0; mi < 4; mi++){
    int ml = wr*64 + mi*16 + li;
    float s = redS[ml][0] + redS[ml][1];
    float q = redQ[ml][0] + redQ[ml][1];
    float mean = s * (1.f/DM);
    float rstd = rsqrtf(q*(1.f/DM) - mean*mean + 1e-5f);
    int m = bm*256 + ml;
#pragma unroll
    for (int ni = 0; ni < 8; ni++){
      int n = wc*128 + ni*16 + g4;
      f32x4 gv = *(const f32x4*)(lng + n);
      f32x4 bv = *(const f32x4*)(lnb + n);
      if (outb){
        bf16x4 o;
#pragma unroll
        for (int r = 0; r < 4; r++) o[r] = (__bf16)((acc[ni][mi][r] - mean)*rstd*gv[r] + bv[r]);
        *(bf16x4*)(outb + (size_t)m*DM + n) = o;
      } else {
        f32x4 o;
#pragma unroll
        for (int r = 0; r < 4; r++) o[r] = (acc[ni][mi][r] - mean)*rstd*gv[r] + bv[r];
        *(f32x4*)(outf + (size_t)m*DM + n) = o;
      }
    }
  }
}

// ---------------- attention: block per sequence, wave per head ----------------
__global__ __launch_bounds__(256) void attn_kernel(const __bf16* __restrict__ qkv, __bf16* __restrict__ ob){
  int b = blockIdx.x;
  int h = threadIdx.x >> 6, lane = threadIdx.x & 63;
  __shared__ __align__(16) __bf16 Qs[NHEAD][L_SEQ][HDIM];
  __shared__ __align__(16) __bf16 Ks[NHEAD][L_SEQ][HDIM];
  __shared__ float Ps[NHEAD][L_SEQ][L_SEQ];
  const __bf16* base = qkv + (size_t)b*L_SEQ*768;
  float V[L_SEQ];
#pragma unroll
  for (int t = 0; t < L_SEQ; t++){
    int sw = lane ^ ((t & 7) << 3);
    Qs[h][t][sw] = base[t*768 + h*64 + lane];
    Ks[h][t][sw] = base[t*768 + 256 + h*64 + lane];
    V[t] = (float)base[t*768 + 512 + h*64 + lane];
  }
  __syncthreads();
  for (int p = lane; p < L_SEQ*L_SEQ; p += 64){
    int q = p / L_SEQ, k = p - q*L_SEQ;
    if (k <= q){
      int qx = (q & 7) << 3, kx = (k & 7) << 3;
      const __bf16* qr = Qs[h][q];
      const __bf16* kr = Ks[h][k];
      float s = 0.f;
#pragma unroll
      for (int d = 0; d < 64; d += 4){
        bf16x4 qa = *(const bf16x4*)(qr + (d ^ qx));
        bf16x4 ka = *(const bf16x4*)(kr + (d ^ kx));
        s += (float)qa[0]*(float)ka[0] + (float)qa[1]*(float)ka[1]
           + (float)qa[2]*(float)ka[2] + (float)qa[3]*(float)ka[3];
      }
      Ps[h][q][k] = s * 0.125f;
    }
  }
  __syncthreads();
  for (int q = 0; q < L_SEQ; q++){
    float v = (lane <= q) ? Ps[h][q][lane] : -1e30f;
    float mx = wred_max(v);
    float e = (lane <= q) ? __expf(v - mx) : 0.f;
    float sm = wred_sum(e);
    if (lane < L_SEQ) Ps[h][q][lane] = e / sm;
  }
  __syncthreads();
  for (int q = 0; q < L_SEQ; q++){
    float o = 0.f;
    for (int k = 0; k <= q; k++) o += Ps[h][q][k] * V[k];
    ob[((size_t)b*L_SEQ + q)*DM + h*64 + lane] = (__bf16)o;
  }
}

// ---------------- per-token heads ----------------
__global__ __launch_bounds__(256) void heads_kernel(
    const float* __restrict__ z,
    const float* __restrict__ cls_w, const float* __restrict__ cls_b,
    const float* __restrict__ eg_w1, const float* __restrict__ eg_b1,
    const float* __restrict__ eg_w2, const float* __restrict__ eg_b2,
    const float* __restrict__ halt_w, const float* __restrict__ halt_b,
    float* __restrict__ halt_out, float* __restrict__ cls_out){
  int m = blockIdx.x*4 + (threadIdx.x >> 6);
  int lane = threadIdx.x & 63;
  int l = m % L_SEQ;
  float4 zv = ((const float4*)(z + (size_t)m*DM))[lane];
  float4 w0 = ((const float4*)(cls_w + ((size_t)l*2 + 0)*DM))[lane];
  float4 w1 = ((const float4*)(cls_w + ((size_t)l*2 + 1)*DM))[lane];
  float c0 = wred_sum(zv.x*w0.x + zv.y*w0.y + zv.z*w0.z + zv.w*w0.w) + cls_b[l*2 + 0];
  float c1 = wred_sum(zv.x*w1.x + zv.y*w1.y + zv.z*w1.z + zv.w*w1.w) + cls_b[l*2 + 1];
  float mx = fmaxf(c0, c1);
  float e0 = __expf(c0 - mx), e1 = __expf(c1 - mx);
  float inv = 1.f/(e0 + e1);
  float p0 = fminf(fmaxf(e0*inv, 1e-10f), 1.f);
  float p1 = fminf(fmaxf(e1*inv, 1e-10f), 1.f);
  float ent = -(p0*__logf(p0) + p1*__logf(p1));
  float entn = fminf(fmaxf(ent * 1.44269504f, 0.f), 1.f);
  const float4* wg = (const float4*)(eg_w1 + ((size_t)l*DM + 4*lane)*8);
  float hacc[8] = {};
#pragma unroll
  for (int dd = 0; dd < 4; dd++){
    float zd = (dd==0) ? zv.x : (dd==1) ? zv.y : (dd==2) ? zv.z : zv.w;
    float4 a = wg[dd*2], b = wg[dd*2 + 1];
    hacc[0] += zd*a.x; hacc[1] += zd*a.y; hacc[2] += zd*a.z; hacc[3] += zd*a.w;
    hacc[4] += zd*b.x; hacc[5] += zd*b.y; hacc[6] += zd*b.z; hacc[7] += zd*b.w;
  }
  float gin = 0.f;
#pragma unroll
  for (int j = 0; j < 8; j++){
    float hj = wred_sum(hacc[j]);
    hj = tanhf(hj + eg_b1[l*8 + j]);
    gin += hj * eg_w2[l*8 + j];
  }
  gin += eg_b2[l];
  float gate = 1.f/(1.f + __expf(-gin));
  float gated = entn * gate;
  const float* hw = halt_w + (size_t)l*257;
  float hp = zv.x*hw[4*lane] + zv.y*hw[4*lane+1] + zv.z*hw[4*lane+2] + zv.w*hw[4*lane+3];
  float hl = wred_sum(hp) + gated*hw[256] + halt_b[l];
  if (lane == 0) halt_out[m] = hl;
  if (lane < 2) cls_out[(size_t)m*2 + lane] = lane ? c1 : c0;
}

extern "C" void kernel_launch(void* const* d_in, const int* in_sizes, int n_in,
                              void* d_out, int out_size, void* d_ws, size_t ws_size,
                              hipStream_t stream){
  const float* teacher = (const float*)d_in[0];
  const float* in_ln_g = (const float*)d_in[1];
  const float* in_ln_b = (const float*)d_in[2];
  const float* proj_w  = (const float*)d_in[3];
  const float* proj_b  = (const float*)d_in[4];
  const float* cosc    = (const float*)d_in[5];
  const float* sinc    = (const float*)d_in[6];
  const float* pre_g   = (const float*)d_in[7];
  const float* pre_b   = (const float*)d_in[8];
  const float* l_ln1_g = (const float*)d_in[9];
  const float* l_ln1_b = (const float*)d_in[10];
  const float* l_inw   = (const float*)d_in[11];
  const float* l_inb   = (const float*)d_in[12];
  const float* l_outw  = (const float*)d_in[13];
  const float* l_outb  = (const float*)d_in[14];
  const float* l_ln2_g = (const float*)d_in[15];
  const float* l_ln2_b = (const float*)d_in[16];
  const float* l_w12   = (const float*)d_in[17];
  const float* l_b12   = (const float*)d_in[18];
  const float* l_w3    = (const float*)d_in[19];
  const float* l_b3    = (const float*)d_in[20];
  const float* post_g  = (const float*)d_in[21];
  const float* post_b  = (const float*)d_in[22];
  const float* eg_w1   = (const float*)d_in[23];
  const float* eg_b1   = (const float*)d_in[24];
  const float* eg_w2   = (const float*)d_in[25];
  const float* eg_b2   = (const float*)d_in[26];
  const float* halt_w  = (const float*)d_in[27];
  const float* halt_b  = (const float*)d_in[28];
  const float* cls_w   = (const float*)d_in[29];
  const float* cls_b   = (const float*)d_in[30];

  float* out = (float*)d_out;
  float* halt_out = out;
  float* cls_out  = out + NTOK;
  float* z_out    = out + NTOK + (size_t)NTOK*NCLS;

  char* ws = (char*)d_ws;
  size_t off = 0;
  auto alloc = [&](size_t bytes){ void* p = ws + off; off += (bytes + 255) & ~(size_t)255; return p; };
  float*  zbuf = (float*) alloc((size_t)NTOK*DM*4);
  __bf16* xnb  = (__bf16*)alloc((size_t)NTOK*DM*2);
  __bf16* qkvb = (__bf16*)alloc((size_t)NTOK*768*2);
  __bf16* obuf = (__bf16*)alloc((size_t)NTOK*DM*2);
  __bf16* bigb = (__bf16*)alloc((size_t)NTOK*1024*2);
  __bf16* w_proj = (__bf16*)alloc((size_t)262144*2);
  __bf16* w_in   = (__bf16*)alloc((size_t)2359296*2);
  __bf16* w_out  = (__bf16*)alloc((size_t)786432*2);
  __bf16* w_12   = (__bf16*)alloc((size_t)6291456*2);
  __bf16* w_3    = (__bf16*)alloc((size_t)3145728*2);

  cvt_bf16_kernel<<<256, 256, 0, stream>>>(proj_w, w_proj, 262144/4);
  cvt_bf16_kernel<<<1024, 256, 0, stream>>>(l_inw, w_in, 2359296/4);
  cvt_bf16_kernel<<<512, 256, 0, stream>>>(l_outw, w_out, 786432/4);
  cvt_bf16_kernel<<<2048, 256, 0, stream>>>(l_w12, w_12, 6291456/4);
  cvt_bf16_kernel<<<1024, 256, 0, stream>>>(l_w3, w_3, 3145728/4);

  ln1024_kernel<<<NTOK, 256, 0, stream>>>(teacher, in_ln_g, in_ln_b, bigb);
  gemm512_kernel<0, 1024><<<192, 512, 0, stream>>>(bigb, w_proj, proj_b, zbuf, nullptr, 256, 1);
  rope_preln_kernel<<<NTOK/4, 256, 0, stream>>>(zbuf, cosc, sinc, pre_g, pre_b, l_ln1_g, l_ln1_b, xnb);

  for (int i = 0; i < NLAYER; i++){
    gemm512_kernel<1, 256><<<576, 512, 0, stream>>>(xnb, w_in + (size_t)i*768*256, l_inb + i*768, nullptr, qkvb, 768, 3);
    attn_kernel<<<NBATCH, 256, 0, stream>>>(qkvb, obuf);
    gemm_ln_kernel<256><<<192, 512, 0, stream>>>(obuf, w_out + (size_t)i*256*256, l_outb + i*256,
                                                 zbuf, l_ln2_g + i*256, l_ln2_b + i*256, xnb, nullptr);
    gemm_glu_kernel<<<1536, 512, 0, stream>>>(xnb, w_12 + (size_t)i*2048*256, l_b12 + i*2048, bigb);
    bool last = (i == NLAYER-1);
    gemm_ln_kernel<1024><<<192, 512, 0, stream>>>(bigb, w_3 + (size_t)i*256*1024, l_b3 + i*256,
                                                  zbuf,
                                                  last ? post_g : l_ln1_g + (i+1)*256,
                                                  last ? post_b : l_ln1_b + (i+1)*256,
                                                  last ? nullptr : xnb,
                                                  last ? z_out : nullptr);
  }

  heads_kernel<<<NTOK/4, 256, 0, stream>>>(z_out, cls_w, cls_b, eg_w1, eg_b1, eg_w2, eg_b2,
                                           halt_w, halt_b, halt_out, cls_out);
}